// Round 3
// baseline (1019.625 us; speedup 1.0000x reference)
//
#include <hip/hip_runtime.h>
#include <hip/hip_bf16.h>
#include <math.h>

// B=2, T=2048, D=1024, H=16, HD=64, INNER=4096. fp32 in/out, bf16 MFMA GEMMs.
constexpr int Dm = 1024;
constexpr int Tt = 2048;
constexpr int NB = 2;
constexpr int NHd = 16;
constexpr int HDd = 64;
constexpr int FF = 4096;
constexpr int NTOK = NB * Tt;

typedef __attribute__((ext_vector_type(8))) short bf16x8;  // 8 bf16 (4 VGPR)
typedef __attribute__((ext_vector_type(4))) float f32x4;   // MFMA acc

struct alignas(8) bh4 { __hip_bfloat16 x, y, z, w; };

#define GLOAD16(gp, lp)                                                        \
  __builtin_amdgcn_global_load_lds(                                            \
      (const __attribute__((address_space(1))) void*)(gp),                     \
      (__attribute__((address_space(3))) void*)(lp), 16, 0, 0)

__device__ __forceinline__ float wave_sum(float v) {
#pragma unroll
  for (int off = 32; off > 0; off >>= 1) v += __shfl_xor(v, off, 64);
  return v;
}

__device__ __forceinline__ float gelu_f(float x) {
  return 0.5f * x * (1.0f + erff(x * 0.7071067811865475f));
}

// ---------- LayerNorm: fp32 in -> bf16 out (GEMM A operand) ----------
__global__ __launch_bounds__(256) void ln_kernel(
    const float* __restrict__ x, const float* __restrict__ g,
    const float* __restrict__ b, __hip_bfloat16* __restrict__ out) {
  __shared__ float red[8];
  const int row = blockIdx.x;
  const int t = threadIdx.x;
  const float4 v = reinterpret_cast<const float4*>(x + (size_t)row * Dm)[t];
  float s = v.x + v.y + v.z + v.w;
  s = wave_sum(s);
  if ((t & 63) == 0) red[t >> 6] = s;
  __syncthreads();
  const float mu = (red[0] + red[1] + red[2] + red[3]) * (1.0f / Dm);
  const float dx = v.x - mu, dy = v.y - mu, dz = v.z - mu, dw = v.w - mu;
  float sq = dx * dx + dy * dy + dz * dz + dw * dw;
  sq = wave_sum(sq);
  if ((t & 63) == 0) red[4 + (t >> 6)] = sq;
  __syncthreads();
  const float var = (red[4] + red[5] + red[6] + red[7]) * (1.0f / Dm);
  const float rstd = 1.0f / sqrtf(var + 1e-5f);
  const float4 gv = reinterpret_cast<const float4*>(g)[t];
  const float4 bv = reinterpret_cast<const float4*>(b)[t];
  bh4 o;
  o.x = __float2bfloat16(dx * rstd * gv.x + bv.x);
  o.y = __float2bfloat16(dy * rstd * gv.y + bv.y);
  o.z = __float2bfloat16(dz * rstd * gv.z + bv.z);
  o.w = __float2bfloat16(dw * rstd * gv.w + bv.w);
  *(bh4*)&out[(size_t)row * Dm + t * 4] = o;
}

// ---------- transpose+cast: W[K][N] fp32 -> Wt[N][K] bf16 ----------
__global__ __launch_bounds__(256) void wt_kernel(
    const float* __restrict__ W, __hip_bfloat16* __restrict__ Wt,
    int K, int N) {
  __shared__ float tile[32][33];
  const int n0 = blockIdx.x * 32, k0 = blockIdx.y * 32;
  const int tx = threadIdx.x & 31, ty = threadIdx.x >> 5;
#pragma unroll
  for (int r = 0; r < 4; ++r)
    tile[ty + 8 * r][tx] = W[(size_t)(k0 + ty + 8 * r) * N + n0 + tx];
  __syncthreads();
#pragma unroll
  for (int r = 0; r < 4; ++r)
    Wt[(size_t)(n0 + ty + 8 * r) * K + k0 + tx] =
        __float2bfloat16(tile[tx][ty + 8 * r]);
}

// ---------- bf16 MFMA GEMM: C = A[MxK](bf16) * Bt[NxK](bf16)^T ----------
// m97 structure: 128x128 tile, BK=64, 4 waves (2x2), 16x16x32 MFMA,
// width-16 global_load_lds staging into linear [row][k] LDS.
enum { EP_QKV = 0, EP_RESID = 1, EP_GELU = 2, EP_DOWN = 3 };

template <int EP>
__global__ __launch_bounds__(256) void gemm_bf16(
    const __hip_bfloat16* __restrict__ A, const __hip_bfloat16* __restrict__ Bt,
    void* __restrict__ Cout, int N, int K,
    const float* __restrict__ bias, const float* __restrict__ resid) {
  __shared__ alignas(16) __hip_bfloat16 As[128 * 64];  // [m][k], 16KB
  __shared__ alignas(16) __hip_bfloat16 Bs[128 * 64];  // [n][k], 16KB
  const int t = threadIdx.x;
  const int wave = t >> 6, lane = t & 63;
  const int m0 = blockIdx.x * 128, n0 = blockIdx.y * 128;
  const int wm = wave >> 1, wn = wave & 1;  // 2x2 wave grid, 64x64 out each
  // staging: wave covers 32 rows (4 issues x 8 rows); lane -> (row,col8)
  const int srow = wave * 32 + (lane >> 3);
  const int scol = (lane & 7) * 8;
  const __hip_bfloat16* Ag = A + (size_t)(m0 + srow) * K + scol;
  const __hip_bfloat16* Bg = Bt + (size_t)(n0 + srow) * K + scol;
  const int lr = lane & 15, lk = lane >> 4;  // MFMA fragment lane split
  f32x4 acc[4][4] = {};
  for (int k0 = 0; k0 < K; k0 += 64) {
#pragma unroll
    for (int i = 0; i < 4; ++i) {
      GLOAD16(Ag + (size_t)i * 8 * K + k0, &As[wave * 2048 + i * 512]);
      GLOAD16(Bg + (size_t)i * 8 * K + k0, &Bs[wave * 2048 + i * 512]);
    }
    __syncthreads();  // compiler drains vmcnt before barrier: tiles ready
#pragma unroll
    for (int ks = 0; ks < 2; ++ks) {
      bf16x8 af[4], bf[4];
#pragma unroll
      for (int mi = 0; mi < 4; ++mi)
        af[mi] = *(const bf16x8*)&As[(wm * 64 + mi * 16 + lr) * 64 + ks * 32 + lk * 8];
#pragma unroll
      for (int ni = 0; ni < 4; ++ni)
        bf[ni] = *(const bf16x8*)&Bs[(wn * 64 + ni * 16 + lr) * 64 + ks * 32 + lk * 8];
#pragma unroll
      for (int mi = 0; mi < 4; ++mi)
#pragma unroll
        for (int ni = 0; ni < 4; ++ni)
          acc[mi][ni] = __builtin_amdgcn_mfma_f32_16x16x32_bf16(
              af[mi], bf[ni], acc[mi][ni], 0, 0, 0);
    }
    __syncthreads();  // compute done before next stage overwrites
  }
  // epilogue: C/D layout col = lane&15, row = (lane>>4)*4 + reg   [m89]
#pragma unroll
  for (int mi = 0; mi < 4; ++mi) {
#pragma unroll
    for (int ni = 0; ni < 4; ++ni) {
      const int col = n0 + wn * 64 + ni * 16 + lr;
      const int row0 = m0 + wm * 64 + mi * 16 + lk * 4;
#pragma unroll
      for (int j = 0; j < 4; ++j) {
        const int row = row0 + j;
        const float v = acc[mi][ni][j];
        if (EP == EP_QKV) {
          const int which = col >> 10, cc = col & 1023;
          const int head = cc >> 6, hd = cc & 63;
          const int bb = row >> 11, tt2 = row & 2047;
          ((float*)Cout)[(size_t)which * (4u << 20) +
                         ((size_t)(bb * NHd + head) * Tt + tt2) * HDd + hd] = v;
        } else if (EP == EP_RESID) {
          ((float*)Cout)[(size_t)row * N + col] =
              v + resid[(size_t)row * N + col];
        } else if (EP == EP_GELU) {
          ((__hip_bfloat16*)Cout)[(size_t)row * N + col] =
              __float2bfloat16(gelu_f(v + bias[col]));
        } else {  // EP_DOWN
          ((float*)Cout)[(size_t)row * N + col] =
              v + bias[col] + resid[(size_t)row * N + col];
        }
      }
    }
  }
}

// ---------- causal flash attention, fp32 compute, bf16 ctx out ----------
__global__ __launch_bounds__(256) void attn_kernel(
    const float* __restrict__ Q, const float* __restrict__ K,
    const float* __restrict__ V, __hip_bfloat16* __restrict__ ctx) {
  __shared__ float Qs[64][68];
  __shared__ float SP[64][68];  // K^T tile during scores, then P
  __shared__ float Vs[64][68];
  const int qt = (int)gridDim.x - 1 - (int)blockIdx.x;
  const int bh = blockIdx.y;
  const int t = threadIdx.x;
  const int r = t >> 2, qd = t & 3;
  const size_t base = (size_t)bh * Tt * HDd;
  {
    const int lr = t >> 2, ld = (t & 3) * 16;
    const float* src = Q + base + (size_t)(qt * 64 + lr) * HDd + ld;
#pragma unroll
    for (int i = 0; i < 4; ++i)
      *(float4*)&Qs[lr][ld + 4 * i] = ((const float4*)src)[i];
  }
  float mrun = -INFINITY, lrun = 0.0f;
  float cacc[16];
#pragma unroll
  for (int i = 0; i < 16; ++i) cacc[i] = 0.0f;

  for (int kt = 0; kt <= qt; ++kt) {
    __syncthreads();
    {
      const int lr = t >> 2, ld = (t & 3) * 16;
      const float* ks = K + base + (size_t)(kt * 64 + lr) * HDd + ld;
#pragma unroll
      for (int i = 0; i < 4; ++i) {
        const float4 kv4 = ((const float4*)ks)[i];
        SP[ld + 4 * i + 0][lr] = kv4.x;
        SP[ld + 4 * i + 1][lr] = kv4.y;
        SP[ld + 4 * i + 2][lr] = kv4.z;
        SP[ld + 4 * i + 3][lr] = kv4.w;
      }
      const float* vsrc = V + base + (size_t)(kt * 64 + lr) * HDd + ld;
#pragma unroll
      for (int i = 0; i < 4; ++i)
        *(float4*)&Vs[lr][ld + 4 * i] = ((const float4*)vsrc)[i];
    }
    __syncthreads();
    float s[16];
#pragma unroll
    for (int i = 0; i < 16; ++i) s[i] = 0.0f;
#pragma unroll 4
    for (int d4 = 0; d4 < 16; ++d4) {
      const float4 qv = *(const float4*)&Qs[r][d4 * 4];
      const float qarr[4] = {qv.x, qv.y, qv.z, qv.w};
#pragma unroll
      for (int dd = 0; dd < 4; ++dd) {
        const int d = d4 * 4 + dd;
        const float qq = qarr[dd];
#pragma unroll
        for (int i4 = 0; i4 < 4; ++i4) {
          const float4 kk4 = *(const float4*)&SP[d][qd * 16 + i4 * 4];
          s[i4 * 4 + 0] = fmaf(qq, kk4.x, s[i4 * 4 + 0]);
          s[i4 * 4 + 1] = fmaf(qq, kk4.y, s[i4 * 4 + 1]);
          s[i4 * 4 + 2] = fmaf(qq, kk4.z, s[i4 * 4 + 2]);
          s[i4 * 4 + 3] = fmaf(qq, kk4.w, s[i4 * 4 + 3]);
        }
      }
    }
    float tmax = -INFINITY;
#pragma unroll
    for (int i = 0; i < 16; ++i) {
      s[i] *= 0.125f;  // 1/sqrt(64)
      if (kt == qt && (qd * 16 + i) > r) s[i] = -INFINITY;
      tmax = fmaxf(tmax, s[i]);
    }
    tmax = fmaxf(tmax, __shfl_xor(tmax, 1, 64));
    tmax = fmaxf(tmax, __shfl_xor(tmax, 2, 64));
    const float mnew = fmaxf(mrun, tmax);
    const float corr = expf(mrun - mnew);
    float rl = 0.0f;
#pragma unroll
    for (int i = 0; i < 16; ++i) {
      const float p = expf(s[i] - mnew);
      s[i] = p;
      rl += p;
    }
    rl += __shfl_xor(rl, 1, 64);
    rl += __shfl_xor(rl, 2, 64);
    lrun = lrun * corr + rl;
    mrun = mnew;
#pragma unroll
    for (int i = 0; i < 16; ++i) cacc[i] *= corr;
    __syncthreads();
#pragma unroll
    for (int i4 = 0; i4 < 4; ++i4) {
      float4 pv;
      pv.x = s[i4 * 4 + 0]; pv.y = s[i4 * 4 + 1];
      pv.z = s[i4 * 4 + 2]; pv.w = s[i4 * 4 + 3];
      *(float4*)&SP[r][qd * 16 + i4 * 4] = pv;
    }
    __syncthreads();
#pragma unroll 4
    for (int kv4 = 0; kv4 < 16; ++kv4) {
      const float4 pp = *(const float4*)&SP[r][kv4 * 4];
      const float parr[4] = {pp.x, pp.y, pp.z, pp.w};
#pragma unroll
      for (int dd = 0; dd < 4; ++dd) {
        const float p = parr[dd];
        const int kv = kv4 * 4 + dd;
#pragma unroll
        for (int i4 = 0; i4 < 4; ++i4) {
          const float4 vv = *(const float4*)&Vs[kv][qd * 16 + i4 * 4];
          cacc[i4 * 4 + 0] = fmaf(p, vv.x, cacc[i4 * 4 + 0]);
          cacc[i4 * 4 + 1] = fmaf(p, vv.y, cacc[i4 * 4 + 1]);
          cacc[i4 * 4 + 2] = fmaf(p, vv.z, cacc[i4 * 4 + 2]);
          cacc[i4 * 4 + 3] = fmaf(p, vv.w, cacc[i4 * 4 + 3]);
        }
      }
    }
  }
  const float inv = 1.0f / lrun;
  const int bb = bh >> 4, hh = bh & 15;
  __hip_bfloat16* dst =
      ctx + (size_t)(bb * Tt + qt * 64 + r) * Dm + hh * HDd + qd * 16;
#pragma unroll
  for (int i4 = 0; i4 < 4; ++i4) {
    bh4 o;
    o.x = __float2bfloat16(cacc[i4 * 4 + 0] * inv);
    o.y = __float2bfloat16(cacc[i4 * 4 + 1] * inv);
    o.z = __float2bfloat16(cacc[i4 * 4 + 2] * inv);
    o.w = __float2bfloat16(cacc[i4 * 4 + 3] * inv);
    *(bh4*)&dst[i4 * 4] = o;
  }
}

extern "C" void kernel_launch(void* const* d_in, const int* in_sizes, int n_in,
                              void* d_out, int out_size, void* d_ws, size_t ws_size,
                              hipStream_t stream) {
  (void)in_sizes; (void)n_in; (void)out_size; (void)ws_size;
  const float* x   = (const float*)d_in[0];
  const float* g1  = (const float*)d_in[1];
  const float* b1  = (const float*)d_in[2];
  const float* Wq  = (const float*)d_in[3];
  const float* Wk  = (const float*)d_in[4];
  const float* Wv  = (const float*)d_in[5];
  const float* Wo  = (const float*)d_in[6];
  const float* g2  = (const float*)d_in[7];
  const float* b2  = (const float*)d_in[8];
  const float* Wup = (const float*)d_in[9];
  const float* bup = (const float*)d_in[10];
  const float* Wdn = (const float*)d_in[11];
  const float* bdn = (const float*)d_in[12];
  float* out = (float*)d_out;
  char* ws = (char*)d_ws;

  // ws layout (bytes), peak 104MB (r1 used 108MB OK):
  __hip_bfloat16* h    = (__hip_bfloat16*)(ws);                 // 8MB  LN out
  float*          qb   = (float*)(ws + (8ull << 20));           // 48MB q|k|v
  __hip_bfloat16* mbuf = (__hip_bfloat16*)(ws + (8ull << 20));  // 32MB overlay (MLP phase)
  __hip_bfloat16* ctx  = (__hip_bfloat16*)(ws + (56ull << 20)); // 8MB
  float*          x1   = (float*)(ws + (64ull << 20));          // 16MB
  __hip_bfloat16* WtQ  = (__hip_bfloat16*)(ws + (80ull << 20)); // 6MB q|k|v
  __hip_bfloat16* WtO  = (__hip_bfloat16*)(ws + (86ull << 20)); // 2MB
  __hip_bfloat16* WtUp = (__hip_bfloat16*)(ws + (88ull << 20)); // 8MB
  __hip_bfloat16* WtDn = (__hip_bfloat16*)(ws + (96ull << 20)); // 8MB

  // weight transpose+cast: W[K][N] fp32 -> Wt[N][K] bf16
  wt_kernel<<<dim3(32, 32), 256, 0, stream>>>(Wq, WtQ, 1024, 1024);
  wt_kernel<<<dim3(32, 32), 256, 0, stream>>>(Wk, WtQ + (1u << 20), 1024, 1024);
  wt_kernel<<<dim3(32, 32), 256, 0, stream>>>(Wv, WtQ + (2u << 20), 1024, 1024);
  wt_kernel<<<dim3(32, 32), 256, 0, stream>>>(Wo, WtO, 1024, 1024);
  wt_kernel<<<dim3(128, 32), 256, 0, stream>>>(Wup, WtUp, 1024, 4096);
  wt_kernel<<<dim3(32, 128), 256, 0, stream>>>(Wdn, WtDn, 4096, 1024);

  // attention sub-block
  ln_kernel<<<NTOK, 256, 0, stream>>>(x, g1, b1, h);
  gemm_bf16<EP_QKV><<<dim3(32, 24), 256, 0, stream>>>(
      h, WtQ, qb, 3072, 1024, nullptr, nullptr);
  attn_kernel<<<dim3(32, 32), 256, 0, stream>>>(
      qb, qb + (4u << 20), qb + (8u << 20), ctx);
  gemm_bf16<EP_RESID><<<dim3(32, 8), 256, 0, stream>>>(
      ctx, WtO, x1, 1024, 1024, nullptr, x);
  // MLP sub-block
  ln_kernel<<<NTOK, 256, 0, stream>>>(x1, g2, b2, h);
  gemm_bf16<EP_GELU><<<dim3(32, 32), 256, 0, stream>>>(
      h, WtUp, mbuf, 4096, 1024, bup, nullptr);
  gemm_bf16<EP_DOWN><<<dim3(32, 8), 256, 0, stream>>>(
      mbuf, WtDn, out, 1024, 4096, bdn, x1);
}

// Round 8
// 514.272 us; speedup vs baseline: 1.9827x; 1.9827x over previous
//
#include <hip/hip_runtime.h>
#include <hip/hip_bf16.h>
#include <math.h>

// B=2, T=2048, D=1024, H=16, HD=64, INNER=4096. fp32 in/out.
// bf16 MFMA GEMMs + bf16 MFMA flash attention.
constexpr int Dm = 1024;
constexpr int Tt = 2048;
constexpr int NB = 2;
constexpr int NHd = 16;
constexpr int HDd = 64;
constexpr int FF = 4096;
constexpr int NTOK = NB * Tt;

typedef __attribute__((ext_vector_type(8))) short bf16x8;  // 8 bf16 (4 VGPR)
typedef __attribute__((ext_vector_type(4))) float f32x4;   // MFMA acc

struct alignas(8) bh4 { __hip_bfloat16 x, y, z, w; };

#define GLOAD16(gp, lp)                                                        \
  __builtin_amdgcn_global_load_lds(                                            \
      (const __attribute__((address_space(1))) void*)(gp),                     \
      (__attribute__((address_space(3))) void*)(lp), 16, 0, 0)

__device__ __forceinline__ float wave_sum(float v) {
#pragma unroll
  for (int off = 32; off > 0; off >>= 1) v += __shfl_xor(v, off, 64);
  return v;
}

__device__ __forceinline__ float gelu_f(float x) {
  return 0.5f * x * (1.0f + erff(x * 0.7071067811865475f));
}

// ---------- LayerNorm: fp32 in -> bf16 out (GEMM A operand) ----------
__global__ __launch_bounds__(256) void ln_kernel(
    const float* __restrict__ x, const float* __restrict__ g,
    const float* __restrict__ b, __hip_bfloat16* __restrict__ out) {
  __shared__ float red[8];
  const int row = blockIdx.x;
  const int t = threadIdx.x;
  const float4 v = reinterpret_cast<const float4*>(x + (size_t)row * Dm)[t];
  float s = v.x + v.y + v.z + v.w;
  s = wave_sum(s);
  if ((t & 63) == 0) red[t >> 6] = s;
  __syncthreads();
  const float mu = (red[0] + red[1] + red[2] + red[3]) * (1.0f / Dm);
  const float dx = v.x - mu, dy = v.y - mu, dz = v.z - mu, dw = v.w - mu;
  float sq = dx * dx + dy * dy + dz * dz + dw * dw;
  sq = wave_sum(sq);
  if ((t & 63) == 0) red[4 + (t >> 6)] = sq;
  __syncthreads();
  const float var = (red[4] + red[5] + red[6] + red[7]) * (1.0f / Dm);
  const float rstd = 1.0f / sqrtf(var + 1e-5f);
  const float4 gv = reinterpret_cast<const float4*>(g)[t];
  const float4 bv = reinterpret_cast<const float4*>(b)[t];
  bh4 o;
  o.x = __float2bfloat16(dx * rstd * gv.x + bv.x);
  o.y = __float2bfloat16(dy * rstd * gv.y + bv.y);
  o.z = __float2bfloat16(dz * rstd * gv.z + bv.z);
  o.w = __float2bfloat16(dw * rstd * gv.w + bv.w);
  *(bh4*)&out[(size_t)row * Dm + t * 4] = o;
}

// ---------- transpose+cast: W[K][N] fp32 -> Wt[N][K] bf16 ----------
__global__ __launch_bounds__(256) void wt_kernel(
    const float* __restrict__ W, __hip_bfloat16* __restrict__ Wt,
    int K, int N) {
  __shared__ float tile[32][33];
  const int n0 = blockIdx.x * 32, k0 = blockIdx.y * 32;
  const int tx = threadIdx.x & 31, ty = threadIdx.x >> 5;
#pragma unroll
  for (int r = 0; r < 4; ++r)
    tile[ty + 8 * r][tx] = W[(size_t)(k0 + ty + 8 * r) * N + n0 + tx];
  __syncthreads();
#pragma unroll
  for (int r = 0; r < 4; ++r)
    Wt[(size_t)(n0 + ty + 8 * r) * K + k0 + tx] =
        __float2bfloat16(tile[tx][ty + 8 * r]);
}

// ---------- bf16 MFMA GEMM: C = A[MxK](bf16) * Bt[NxK](bf16)^T ----------
enum { EP_QKV = 0, EP_RESID = 1, EP_GELU = 2, EP_DOWN = 3 };

template <int EP>
__global__ __launch_bounds__(256) void gemm_bf16(
    const __hip_bfloat16* __restrict__ A, const __hip_bfloat16* __restrict__ Bt,
    void* __restrict__ Cout, int N, int K,
    const float* __restrict__ bias, const float* __restrict__ resid) {
  __shared__ alignas(16) __hip_bfloat16 As[128 * 64];  // [m][k], 16KB
  __shared__ alignas(16) __hip_bfloat16 Bs[128 * 64];  // [n][k], 16KB
  const int t = threadIdx.x;
  const int wave = t >> 6, lane = t & 63;
  const int m0 = blockIdx.x * 128, n0 = blockIdx.y * 128;
  const int wm = wave >> 1, wn = wave & 1;  // 2x2 wave grid, 64x64 out each
  const int srow = wave * 32 + (lane >> 3);
  const int scol = (lane & 7) * 8;
  const __hip_bfloat16* Ag = A + (size_t)(m0 + srow) * K + scol;
  const __hip_bfloat16* Bg = Bt + (size_t)(n0 + srow) * K + scol;
  const int lr = lane & 15, lk = lane >> 4;
  f32x4 acc[4][4] = {};
  for (int k0 = 0; k0 < K; k0 += 64) {
#pragma unroll
    for (int i = 0; i < 4; ++i) {
      GLOAD16(Ag + (size_t)i * 8 * K + k0, &As[wave * 2048 + i * 512]);
      GLOAD16(Bg + (size_t)i * 8 * K + k0, &Bs[wave * 2048 + i * 512]);
    }
    __syncthreads();
#pragma unroll
    for (int ks = 0; ks < 2; ++ks) {
      bf16x8 af[4], bf[4];
#pragma unroll
      for (int mi = 0; mi < 4; ++mi)
        af[mi] = *(const bf16x8*)&As[(wm * 64 + mi * 16 + lr) * 64 + ks * 32 + lk * 8];
#pragma unroll
      for (int ni = 0; ni < 4; ++ni)
        bf[ni] = *(const bf16x8*)&Bs[(wn * 64 + ni * 16 + lr) * 64 + ks * 32 + lk * 8];
#pragma unroll
      for (int mi = 0; mi < 4; ++mi)
#pragma unroll
        for (int ni = 0; ni < 4; ++ni)
          acc[mi][ni] = __builtin_amdgcn_mfma_f32_16x16x32_bf16(
              af[mi], bf[ni], acc[mi][ni], 0, 0, 0);
    }
    __syncthreads();
  }
  // epilogue: C/D layout col = lane&15, row = (lane>>4)*4 + reg
#pragma unroll
  for (int mi = 0; mi < 4; ++mi) {
#pragma unroll
    for (int ni = 0; ni < 4; ++ni) {
      const int col = n0 + wn * 64 + ni * 16 + lr;
      const int row0 = m0 + wm * 64 + mi * 16 + lk * 4;
#pragma unroll
      for (int j = 0; j < 4; ++j) {
        const int row = row0 + j;
        const float v = acc[mi][ni][j];
        if (EP == EP_QKV) {
          const int which = col >> 10, cc = col & 1023;
          const int head = cc >> 6, hd = cc & 63;
          const int bb = row >> 11, tt2 = row & 2047;
          ((__hip_bfloat16*)Cout)[(size_t)which * (4u << 20) +
              ((size_t)(bb * NHd + head) * Tt + tt2) * HDd + hd] =
              __float2bfloat16(v);
        } else if (EP == EP_RESID) {
          ((float*)Cout)[(size_t)row * N + col] =
              v + resid[(size_t)row * N + col];
        } else if (EP == EP_GELU) {
          ((__hip_bfloat16*)Cout)[(size_t)row * N + col] =
              __float2bfloat16(gelu_f(v + bias[col]));
        } else {  // EP_DOWN
          ((float*)Cout)[(size_t)row * N + col] =
              v + bias[col] + resid[(size_t)row * N + col];
        }
      }
    }
  }
}

// ---------- causal flash attention, bf16 MFMA ----------
// grid (32 qtiles, 32 bh); 4 waves, wave w owns q rows [w*16, w*16+16).
// Fragment conventions as validated by gemm_bf16: A/B row|col = lane&15,
// k = (lane>>4)*8+e; C/D col = lane&15, row = (lane>>4)*4+reg.
__global__ __launch_bounds__(256) void attn_mfma(
    const __hip_bfloat16* __restrict__ Q, const __hip_bfloat16* __restrict__ K,
    const __hip_bfloat16* __restrict__ V, __hip_bfloat16* __restrict__ ctx) {
  __shared__ alignas(16) __hip_bfloat16 Ks[64 * 64];      // [kv][d] XOR-swz, 8KB
  __shared__ alignas(16) __hip_bfloat16 VTs[64 * 72];     // [d][kv] swz ld=72, 9KB
  __shared__ alignas(16) __hip_bfloat16 Pl[4 * 16 * 72];  // per-wave P[q][kv], 9KB
  const int qt = (int)gridDim.x - 1 - (int)blockIdx.x;  // longest first
  const int bh = blockIdx.y;
  const int t = threadIdx.x;
  const int w = t >> 6, l = t & 63;
  const int r = l & 15, g = l >> 4;
  const size_t base = (size_t)bh * (size_t)Tt * HDd;
  // Q fragments register-resident for the whole kernel
  bf16x8 qf[2];
  {
    const __hip_bfloat16* qrow = Q + base + (size_t)(qt * 64 + w * 16 + r) * HDd;
    qf[0] = *(const bf16x8*)(qrow + g * 8);
    qf[1] = *(const bf16x8*)(qrow + 32 + g * 8);
  }
  float mrun[4], lrun[4];
  f32x4 oacc[4];
#pragma unroll
  for (int j = 0; j < 4; ++j) { mrun[j] = -1e30f; lrun[j] = 0.0f; }
#pragma unroll
  for (int db = 0; db < 4; ++db) oacc[db] = f32x4{0.f, 0.f, 0.f, 0.f};

  for (int kt = 0; kt <= qt; ++kt) {
    __syncthreads();  // prev iter's Ks/VTs reads complete
    {  // stage K: linear LDS dst, inverse-swizzled global src (rule #21)
      const int kr = t >> 3;                // 0..31
      const int cb = (t & 7) ^ (kr & 7);    // pre-swizzled 8-elem col block
#pragma unroll
      for (int i = 0; i < 2; ++i)
        GLOAD16(K + base + (size_t)(kt * 64 + i * 32 + kr) * HDd + cb * 8,
                (char*)Ks + i * 4096 + t * 16);
    }
    {  // stage V^T: reg load + swizzled scalar transpose writes
      const int kv = t >> 2, d0 = (t & 3) * 16;
      const __hip_bfloat16* vr = V + base + (size_t)(kt * 64 + kv) * HDd + d0;
      const bf16x8 v0 = *(const bf16x8*)vr;
      const bf16x8 v1 = *(const bf16x8*)(vr + 8);
      short* vts = (short*)VTs;
#pragma unroll
      for (int j = 0; j < 8; ++j) {  // (d&7)==j for both halves
        vts[(d0 + j) * 72 + (kv ^ (j << 3))] = v0[j];
        vts[(d0 + 8 + j) * 72 + (kv ^ (j << 3))] = v1[j];
      }
    }
    __syncthreads();  // tiles ready
    // ---- S = Q K^T ----
    f32x4 sacc[4];
#pragma unroll
    for (int c4 = 0; c4 < 4; ++c4) sacc[c4] = f32x4{0.f, 0.f, 0.f, 0.f};
#pragma unroll
    for (int c4 = 0; c4 < 4; ++c4) {
      const int krow = c4 * 16 + r;
#pragma unroll
      for (int ks = 0; ks < 2; ++ks) {
        const int cb = (ks * 4 + g) ^ (krow & 7);
        const bf16x8 kf = *(const bf16x8*)&Ks[krow * 64 + cb * 8];
        sacc[c4] = __builtin_amdgcn_mfma_f32_16x16x32_bf16(
            qf[ks], kf, sacc[c4], 0, 0, 0);
      }
    }
    // ---- online softmax (rows = w*16 + g*4 + j, cols = c4*16 + r) ----
    float sc[4][4];
#pragma unroll
    for (int c4 = 0; c4 < 4; ++c4)
#pragma unroll
      for (int j = 0; j < 4; ++j) {
        float s = sacc[c4][j] * 0.125f;
        if (kt == qt && (c4 * 16 + r) > (w * 16 + g * 4 + j)) s = -1e30f;
        sc[c4][j] = s;
      }
#pragma unroll
    for (int j = 0; j < 4; ++j) {
      float mj = fmaxf(fmaxf(sc[0][j], sc[1][j]), fmaxf(sc[2][j], sc[3][j]));
      mj = fmaxf(mj, __shfl_xor(mj, 1, 64));
      mj = fmaxf(mj, __shfl_xor(mj, 2, 64));
      mj = fmaxf(mj, __shfl_xor(mj, 4, 64));
      mj = fmaxf(mj, __shfl_xor(mj, 8, 64));
      const float mn = fmaxf(mrun[j], mj);
      const float corr = __expf(mrun[j] - mn);
      float rs = 0.0f;
#pragma unroll
      for (int c4 = 0; c4 < 4; ++c4) {
        const float p = __expf(sc[c4][j] - mn);
        rs += p;
        Pl[w * 1152 + (g * 4 + j) * 72 + c4 * 16 + r] = __float2bfloat16(p);
      }
      rs += __shfl_xor(rs, 1, 64);
      rs += __shfl_xor(rs, 2, 64);
      rs += __shfl_xor(rs, 4, 64);
      rs += __shfl_xor(rs, 8, 64);
      lrun[j] = lrun[j] * corr + rs;
      mrun[j] = mn;
#pragma unroll
      for (int db = 0; db < 4; ++db) oacc[db][j] *= corr;
    }
    // ---- O += P V  (P per-wave: same-wave write/read, no barrier) ----
#pragma unroll
    for (int kh = 0; kh < 2; ++kh) {
      const bf16x8 pa = *(const bf16x8*)&Pl[w * 1152 + r * 72 + kh * 32 + g * 8];
#pragma unroll
      for (int db = 0; db < 4; ++db) {
        const int d = db * 16 + r;
        const int cb = (kh * 4 + g) ^ (d & 7);
        const bf16x8 vf = *(const bf16x8*)&VTs[d * 72 + cb * 8];
        oacc[db] = __builtin_amdgcn_mfma_f32_16x16x32_bf16(
            pa, vf, oacc[db], 0, 0, 0);
      }
    }
  }
  // epilogue: ctx[tok][h*64+d] bf16
  const int b = bh >> 4, hh = bh & 15;
#pragma unroll
  for (int j = 0; j < 4; ++j) {
    const float inv = 1.0f / lrun[j];
    const size_t tok = (size_t)b * Tt + qt * 64 + w * 16 + g * 4 + j;
#pragma unroll
    for (int db = 0; db < 4; ++db)
      ctx[tok * Dm + hh * 64 + db * 16 + r] =
          __float2bfloat16(oacc[db][j] * inv);
  }
}

extern "C" void kernel_launch(void* const* d_in, const int* in_sizes, int n_in,
                              void* d_out, int out_size, void* d_ws, size_t ws_size,
                              hipStream_t stream) {
  (void)in_sizes; (void)n_in; (void)out_size; (void)ws_size;
  const float* x   = (const float*)d_in[0];
  const float* g1  = (const float*)d_in[1];
  const float* b1  = (const float*)d_in[2];
  const float* Wq  = (const float*)d_in[3];
  const float* Wk  = (const float*)d_in[4];
  const float* Wv  = (const float*)d_in[5];
  const float* Wo  = (const float*)d_in[6];
  const float* g2  = (const float*)d_in[7];
  const float* b2  = (const float*)d_in[8];
  const float* Wup = (const float*)d_in[9];
  const float* bup = (const float*)d_in[10];
  const float* Wdn = (const float*)d_in[11];
  const float* bdn = (const float*)d_in[12];
  float* out = (float*)d_out;
  char* ws = (char*)d_ws;

  // ws layout (bytes), peak 80MB:
  __hip_bfloat16* h    = (__hip_bfloat16*)(ws);                 // 8MB LN out
  __hip_bfloat16* qkv  = (__hip_bfloat16*)(ws + (8ull << 20));  // 24MB q|k|v bf16
  __hip_bfloat16* ctx  = (__hip_bfloat16*)(ws + (32ull << 20)); // 8MB
  float*          x1   = (float*)(ws + (40ull << 20));          // 16MB
  __hip_bfloat16* mbuf = (__hip_bfloat16*)(ws + (8ull << 20));  // 32MB overlay (qkv+ctx dead)
  __hip_bfloat16* WtQ  = (__hip_bfloat16*)(ws + (56ull << 20)); // 6MB q|k|v
  __hip_bfloat16* WtO  = (__hip_bfloat16*)(ws + (62ull << 20)); // 2MB
  __hip_bfloat16* WtUp = (__hip_bfloat16*)(ws + (64ull << 20)); // 8MB
  __hip_bfloat16* WtDn = (__hip_bfloat16*)(ws + (72ull << 20)); // 8MB

  wt_kernel<<<dim3(32, 32), 256, 0, stream>>>(Wq, WtQ, 1024, 1024);
  wt_kernel<<<dim3(32, 32), 256, 0, stream>>>(Wk, WtQ + (1u << 20), 1024, 1024);
  wt_kernel<<<dim3(32, 32), 256, 0, stream>>>(Wv, WtQ + (2u << 20), 1024, 1024);
  wt_kernel<<<dim3(32, 32), 256, 0, stream>>>(Wo, WtO, 1024, 1024);
  wt_kernel<<<dim3(128, 32), 256, 0, stream>>>(Wup, WtUp, 1024, 4096);
  wt_kernel<<<dim3(32, 128), 256, 0, stream>>>(Wdn, WtDn, 4096, 1024);

  // attention sub-block
  ln_kernel<<<NTOK, 256, 0, stream>>>(x, g1, b1, h);
  gemm_bf16<EP_QKV><<<dim3(32, 24), 256, 0, stream>>>(
      h, WtQ, qkv, 3072, 1024, nullptr, nullptr);
  attn_mfma<<<dim3(32, 32), 256, 0, stream>>>(
      qkv, qkv + (4u << 20), qkv + (8u << 20), ctx);
  gemm_bf16<EP_RESID><<<dim3(32, 8), 256, 0, stream>>>(
      ctx, WtO, x1, 1024, 1024, nullptr, x);
  // MLP sub-block
  ln_kernel<<<NTOK, 256, 0, stream>>>(x1, g2, b2, h);
  gemm_bf16<EP_GELU><<<dim3(32, 32), 256, 0, stream>>>(
      h, WtUp, mbuf, 4096, 1024, bup, nullptr);
  gemm_bf16<EP_DOWN><<<dim3(32, 8), 256, 0, stream>>>(
      mbuf, WtDn, out, 1024, 4096, bdn, x1);
}

// Round 12
// 441.823 us; speedup vs baseline: 2.3078x; 1.1640x over previous
//
#include <hip/hip_runtime.h>
#include <hip/hip_bf16.h>
#include <math.h>

// B=2, T=2048, D=1024, H=16, HD=64, INNER=4096. fp32 in/out.
// bf16 MFMA GEMMs + bf16 MFMA flash attention (swapped-QK^T, paired q-tiles).
constexpr int Dm = 1024;
constexpr int Tt = 2048;
constexpr int NB = 2;
constexpr int NHd = 16;
constexpr int HDd = 64;
constexpr int FF = 4096;
constexpr int NTOK = NB * Tt;

typedef __attribute__((ext_vector_type(8))) short bf16x8;  // 8 bf16 (4 VGPR)
typedef __attribute__((ext_vector_type(4))) float f32x4;   // MFMA acc

struct alignas(8) bh4 { __hip_bfloat16 x, y, z, w; };

#define GLOAD16(gp, lp)                                                        \
  __builtin_amdgcn_global_load_lds(                                            \
      (const __attribute__((address_space(1))) void*)(gp),                     \
      (__attribute__((address_space(3))) void*)(lp), 16, 0, 0)

__device__ __forceinline__ float wave_sum(float v) {
#pragma unroll
  for (int off = 32; off > 0; off >>= 1) v += __shfl_xor(v, off, 64);
  return v;
}

__device__ __forceinline__ float gelu_f(float x) {
  return 0.5f * x * (1.0f + erff(x * 0.7071067811865475f));
}

// ---------- LayerNorm: fp32 in -> bf16 out (GEMM A operand) ----------
__global__ __launch_bounds__(256) void ln_kernel(
    const float* __restrict__ x, const float* __restrict__ g,
    const float* __restrict__ b, __hip_bfloat16* __restrict__ out) {
  __shared__ float red[8];
  const int row = blockIdx.x;
  const int t = threadIdx.x;
  const float4 v = reinterpret_cast<const float4*>(x + (size_t)row * Dm)[t];
  float s = v.x + v.y + v.z + v.w;
  s = wave_sum(s);
  if ((t & 63) == 0) red[t >> 6] = s;
  __syncthreads();
  const float mu = (red[0] + red[1] + red[2] + red[3]) * (1.0f / Dm);
  const float dx = v.x - mu, dy = v.y - mu, dz = v.z - mu, dw = v.w - mu;
  float sq = dx * dx + dy * dy + dz * dz + dw * dw;
  sq = wave_sum(sq);
  if ((t & 63) == 0) red[4 + (t >> 6)] = sq;
  __syncthreads();
  const float var = (red[4] + red[5] + red[6] + red[7]) * (1.0f / Dm);
  const float rstd = 1.0f / sqrtf(var + 1e-5f);
  const float4 gv = reinterpret_cast<const float4*>(g)[t];
  const float4 bv = reinterpret_cast<const float4*>(b)[t];
  bh4 o;
  o.x = __float2bfloat16(dx * rstd * gv.x + bv.x);
  o.y = __float2bfloat16(dy * rstd * gv.y + bv.y);
  o.z = __float2bfloat16(dz * rstd * gv.z + bv.z);
  o.w = __float2bfloat16(dw * rstd * gv.w + bv.w);
  *(bh4*)&out[(size_t)row * Dm + t * 4] = o;
}

// ---------- transpose+cast: W[K][N] fp32 -> Wt[N][K] bf16 ----------
__global__ __launch_bounds__(256) void wt_kernel(
    const float* __restrict__ W, __hip_bfloat16* __restrict__ Wt,
    int K, int N) {
  __shared__ float tile[32][33];
  const int n0 = blockIdx.x * 32, k0 = blockIdx.y * 32;
  const int tx = threadIdx.x & 31, ty = threadIdx.x >> 5;
#pragma unroll
  for (int r = 0; r < 4; ++r)
    tile[ty + 8 * r][tx] = W[(size_t)(k0 + ty + 8 * r) * N + n0 + tx];
  __syncthreads();
#pragma unroll
  for (int r = 0; r < 4; ++r)
    Wt[(size_t)(n0 + ty + 8 * r) * K + k0 + tx] =
        __float2bfloat16(tile[tx][ty + 8 * r]);
}

// ---------- bf16 MFMA GEMM: C = A[MxK](bf16) * Bt[NxK](bf16)^T ----------
enum { EP_QKV = 0, EP_RESID = 1, EP_GELU = 2, EP_DOWN = 3 };

template <int EP>
__global__ __launch_bounds__(256) void gemm_bf16(
    const __hip_bfloat16* __restrict__ A, const __hip_bfloat16* __restrict__ Bt,
    void* __restrict__ Cout, int N, int K,
    const float* __restrict__ bias, const float* __restrict__ resid) {
  __shared__ alignas(16) __hip_bfloat16 As[128 * 64];  // [m][k], 16KB
  __shared__ alignas(16) __hip_bfloat16 Bs[128 * 64];  // [n][k], 16KB
  const int t = threadIdx.x;
  const int wave = t >> 6, lane = t & 63;
  const int m0 = blockIdx.x * 128, n0 = blockIdx.y * 128;
  const int wm = wave >> 1, wn = wave & 1;  // 2x2 wave grid, 64x64 out each
  const int srow = wave * 32 + (lane >> 3);
  const int scol = (lane & 7) * 8;
  const __hip_bfloat16* Ag = A + (size_t)(m0 + srow) * K + scol;
  const __hip_bfloat16* Bg = Bt + (size_t)(n0 + srow) * K + scol;
  const int lr = lane & 15, lk = lane >> 4;
  f32x4 acc[4][4] = {};
  for (int k0 = 0; k0 < K; k0 += 64) {
#pragma unroll
    for (int i = 0; i < 4; ++i) {
      GLOAD16(Ag + (size_t)i * 8 * K + k0, &As[wave * 2048 + i * 512]);
      GLOAD16(Bg + (size_t)i * 8 * K + k0, &Bs[wave * 2048 + i * 512]);
    }
    __syncthreads();
#pragma unroll
    for (int ks = 0; ks < 2; ++ks) {
      bf16x8 af[4], bf[4];
#pragma unroll
      for (int mi = 0; mi < 4; ++mi)
        af[mi] = *(const bf16x8*)&As[(wm * 64 + mi * 16 + lr) * 64 + ks * 32 + lk * 8];
#pragma unroll
      for (int ni = 0; ni < 4; ++ni)
        bf[ni] = *(const bf16x8*)&Bs[(wn * 64 + ni * 16 + lr) * 64 + ks * 32 + lk * 8];
#pragma unroll
      for (int mi = 0; mi < 4; ++mi)
#pragma unroll
        for (int ni = 0; ni < 4; ++ni)
          acc[mi][ni] = __builtin_amdgcn_mfma_f32_16x16x32_bf16(
              af[mi], bf[ni], acc[mi][ni], 0, 0, 0);
    }
    __syncthreads();
  }
  // epilogue: C/D layout col = lane&15, row = (lane>>4)*4 + reg
#pragma unroll
  for (int mi = 0; mi < 4; ++mi) {
#pragma unroll
    for (int ni = 0; ni < 4; ++ni) {
      const int col = n0 + wn * 64 + ni * 16 + lr;
      const int row0 = m0 + wm * 64 + mi * 16 + lk * 4;
#pragma unroll
      for (int j = 0; j < 4; ++j) {
        const int row = row0 + j;
        const float v = acc[mi][ni][j];
        if (EP == EP_QKV) {
          const int which = col >> 10, cc = col & 1023;
          const int head = cc >> 6, hd = cc & 63;
          const int bb = row >> 11, tt2 = row & 2047;
          ((__hip_bfloat16*)Cout)[(size_t)which * (4u << 20) +
              ((size_t)(bb * NHd + head) * Tt + tt2) * HDd + hd] =
              __float2bfloat16(v);
        } else if (EP == EP_RESID) {
          ((float*)Cout)[(size_t)row * N + col] =
              v + resid[(size_t)row * N + col];
        } else if (EP == EP_GELU) {
          ((__hip_bfloat16*)Cout)[(size_t)row * N + col] =
              __float2bfloat16(gelu_f(v + bias[col]));
        } else {  // EP_DOWN
          ((float*)Cout)[(size_t)row * N + col] =
              v + bias[col] + resid[(size_t)row * N + col];
        }
      }
    }
  }
}

// ---------- causal flash attention, bf16 MFMA, swapped QK^T ----------
// grid (16 qt-pairs, 32 bh); block = 4 waves; block does q-tiles {qp, 31-qp}
// sequentially => uniform 33 iters/block. Wave w owns q rows [w*16, w*16+16).
// Swapped S^T = mfma(K, Q): lane (r,g) holds S[kv=c4*16+g*4+j][q=w*16+r]
// => softmax is lane-local in kv, combine across g via 2 shfl.
__global__ __launch_bounds__(256) void attn_mfma(
    const __hip_bfloat16* __restrict__ Q, const __hip_bfloat16* __restrict__ K,
    const __hip_bfloat16* __restrict__ V, __hip_bfloat16* __restrict__ ctx) {
  __shared__ alignas(16) __hip_bfloat16 Ks[64 * 64];   // [kv][d] XOR-swz, 8KB
  __shared__ alignas(16) unsigned int VTu[64 * 36];    // V^T [d][kv-pair] swz, 9KB
  __shared__ alignas(16) __hip_bfloat16 Pl[4][16 * 72]; // per-wave P[q][kv] swz, 9KB
  const int qp = blockIdx.x;  // 0..15
  const int bh = blockIdx.y;
  const int t = threadIdx.x;
  const int w = t >> 6, l = t & 63;
  const int r = l & 15, g = l >> 4;
  const int rho = r & 7;
  const size_t base = (size_t)bh * (size_t)Tt * HDd;

#pragma unroll 1
  for (int ph = 0; ph < 2; ++ph) {
    const int qt = ph ? (31 - qp) : qp;
    // Q fragments (B-operand: row=q=lane&15, k=(lane>>4)*8+e)
    bf16x8 qf[2];
    {
      const __hip_bfloat16* qrow = Q + base + (size_t)(qt * 64 + w * 16 + r) * HDd;
      qf[0] = *(const bf16x8*)(qrow + g * 8);
      qf[1] = *(const bf16x8*)(qrow + 32 + g * 8);
    }
    float mrun = -1e30f, lrun = 0.0f;  // per-lane, for q = w*16 + r
    f32x4 oacc[4];
#pragma unroll
    for (int db = 0; db < 4; ++db) oacc[db] = f32x4{0.f, 0.f, 0.f, 0.f};

    for (int kt = 0; kt <= qt; ++kt) {
      __syncthreads();  // prev iter reads (and prev phase) complete
      {  // stage K: linear LDS dst, inverse-swizzled global src
        const int kr = t >> 3;
        const int cb = (t & 7) ^ (kr & 7);
#pragma unroll
        for (int i = 0; i < 2; ++i)
          GLOAD16(K + base + (size_t)(kt * 64 + i * 32 + kr) * HDd + cb * 8,
                  (char*)Ks + i * 4096 + t * 16);
      }
      {  // stage V^T: kv-pair packed u32 writes, conflict-free swizzle
        const int kvp = t >> 3, dblk = t & 7;
        const __hip_bfloat16* vr =
            V + base + (size_t)(kt * 64 + kvp * 2) * HDd + dblk * 8;
        const bf16x8 v0 = *(const bf16x8*)vr;
        const bf16x8 v1 = *(const bf16x8*)(vr + HDd);
        const int kvs = kvp ^ (dblk << 2);
#pragma unroll
        for (int j = 0; j < 8; ++j) {
          const unsigned int pk = (unsigned int)(unsigned short)v0[j] |
                                  ((unsigned int)(unsigned short)v1[j] << 16);
          VTu[(dblk * 8 + j) * 36 + kvs] = pk;
        }
      }
      __syncthreads();  // tiles ready
      // ---- S^T = K Q^T : D[kv][q] ----
      f32x4 sacc[4];
#pragma unroll
      for (int c4 = 0; c4 < 4; ++c4) sacc[c4] = f32x4{0.f, 0.f, 0.f, 0.f};
#pragma unroll
      for (int c4 = 0; c4 < 4; ++c4) {
        const int krow = c4 * 16 + r;
#pragma unroll
        for (int ks = 0; ks < 2; ++ks) {
          const int cb = (ks * 4 + g) ^ (krow & 7);
          const bf16x8 kf = *(const bf16x8*)&Ks[krow * 64 + cb * 8];
          sacc[c4] = __builtin_amdgcn_mfma_f32_16x16x32_bf16(
              kf, qf[ks], sacc[c4], 0, 0, 0);
        }
      }
      // ---- lane-local online softmax (q = w*16+r; kv = c4*16+g*4+j) ----
      float sc[16];
      float pm = -1e30f;
#pragma unroll
      for (int c4 = 0; c4 < 4; ++c4)
#pragma unroll
        for (int j = 0; j < 4; ++j) {
          float s = sacc[c4][j] * 0.125f;  // 1/sqrt(64)
          if (kt == qt && (c4 * 16 + g * 4 + j) > (w * 16 + r)) s = -1e30f;
          sc[c4 * 4 + j] = s;
          pm = fmaxf(pm, s);
        }
      pm = fmaxf(pm, __shfl_xor(pm, 16, 64));
      pm = fmaxf(pm, __shfl_xor(pm, 32, 64));
      const float mn = fmaxf(mrun, pm);
      const float corr = __expf(mrun - mn);
      mrun = mn;
      float ps = 0.0f;
#pragma unroll
      for (int c4 = 0; c4 < 4; ++c4)
#pragma unroll
        for (int j = 0; j < 4; ++j) {
          const float p = __expf(sc[c4 * 4 + j] - mn);
          ps += p;
          Pl[w][r * 72 + ((c4 * 16 + g * 4 + j) ^ (rho << 3))] =
              __float2bfloat16(p);
        }
      ps += __shfl_xor(ps, 16, 64);
      ps += __shfl_xor(ps, 32, 64);
      lrun = lrun * corr + ps;
      // route corr to O rows (oacc[db][j] is q = w*16 + g*4 + j)
#pragma unroll
      for (int j = 0; j < 4; ++j) {
        const float cj = __shfl(corr, g * 4 + j, 64);
#pragma unroll
        for (int db = 0; db < 4; ++db) oacc[db][j] *= cj;
      }
      // ---- O += P V (P per-wave: same-wave write/read) ----
#pragma unroll
      for (int kh = 0; kh < 2; ++kh) {
        const bf16x8 pa =
            *(const bf16x8*)&Pl[w][r * 72 + ((kh * 32 + g * 8) ^ (rho << 3))];
#pragma unroll
        for (int db = 0; db < 4; ++db) {
          const int d = db * 16 + r;
          const bf16x8 vf = *(const bf16x8*)&VTu[d * 36 +
              (((kh * 4 + g) << 2) ^ ((d >> 3) << 2))];
          oacc[db] = __builtin_amdgcn_mfma_f32_16x16x32_bf16(
              pa, vf, oacc[db], 0, 0, 0);
        }
      }
    }
    // ---- epilogue: ctx[tok][h*64+d] bf16 ----
    const int b = bh >> 4, hh = bh & 15;
#pragma unroll
    for (int j = 0; j < 4; ++j) {
      const float lj = __shfl(lrun, g * 4 + j, 64);
      const float inv = 1.0f / lj;
      const size_t tok = (size_t)b * Tt + qt * 64 + w * 16 + g * 4 + j;
#pragma unroll
      for (int db = 0; db < 4; ++db)
        ctx[tok * Dm + hh * 64 + db * 16 + r] =
            __float2bfloat16(oacc[db][j] * inv);
    }
  }
}

extern "C" void kernel_launch(void* const* d_in, const int* in_sizes, int n_in,
                              void* d_out, int out_size, void* d_ws, size_t ws_size,
                              hipStream_t stream) {
  (void)in_sizes; (void)n_in; (void)out_size; (void)ws_size;
  const float* x   = (const float*)d_in[0];
  const float* g1  = (const float*)d_in[1];
  const float* b1  = (const float*)d_in[2];
  const float* Wq  = (const float*)d_in[3];
  const float* Wk  = (const float*)d_in[4];
  const float* Wv  = (const float*)d_in[5];
  const float* Wo  = (const float*)d_in[6];
  const float* g2  = (const float*)d_in[7];
  const float* b2  = (const float*)d_in[8];
  const float* Wup = (const float*)d_in[9];
  const float* bup = (const float*)d_in[10];
  const float* Wdn = (const float*)d_in[11];
  const float* bdn = (const float*)d_in[12];
  float* out = (float*)d_out;
  char* ws = (char*)d_ws;

  // ws layout (bytes), peak 80MB:
  __hip_bfloat16* h    = (__hip_bfloat16*)(ws);                 // 8MB LN out
  __hip_bfloat16* qkv  = (__hip_bfloat16*)(ws + (8ull << 20));  // 24MB q|k|v bf16
  __hip_bfloat16* ctx  = (__hip_bfloat16*)(ws + (32ull << 20)); // 8MB
  float*          x1   = (float*)(ws + (40ull << 20));          // 16MB
  __hip_bfloat16* mbuf = (__hip_bfloat16*)(ws + (8ull << 20));  // 32MB overlay (qkv+ctx dead)
  __hip_bfloat16* WtQ  = (__hip_bfloat16*)(ws + (56ull << 20)); // 6MB q|k|v
  __hip_bfloat16* WtO  = (__hip_bfloat16*)(ws + (62ull << 20)); // 2MB
  __hip_bfloat16* WtUp = (__hip_bfloat16*)(ws + (64ull << 20)); // 8MB
  __hip_bfloat16* WtDn = (__hip_bfloat16*)(ws + (72ull << 20)); // 8MB

  wt_kernel<<<dim3(32, 32), 256, 0, stream>>>(Wq, WtQ, 1024, 1024);
  wt_kernel<<<dim3(32, 32), 256, 0, stream>>>(Wk, WtQ + (1u << 20), 1024, 1024);
  wt_kernel<<<dim3(32, 32), 256, 0, stream>>>(Wv, WtQ + (2u << 20), 1024, 1024);
  wt_kernel<<<dim3(32, 32), 256, 0, stream>>>(Wo, WtO, 1024, 1024);
  wt_kernel<<<dim3(128, 32), 256, 0, stream>>>(Wup, WtUp, 1024, 4096);
  wt_kernel<<<dim3(32, 128), 256, 0, stream>>>(Wdn, WtDn, 4096, 1024);

  // attention sub-block
  ln_kernel<<<NTOK, 256, 0, stream>>>(x, g1, b1, h);
  gemm_bf16<EP_QKV><<<dim3(32, 24), 256, 0, stream>>>(
      h, WtQ, qkv, 3072, 1024, nullptr, nullptr);
  attn_mfma<<<dim3(16, 32), 256, 0, stream>>>(
      qkv, qkv + (4u << 20), qkv + (8u << 20), ctx);
  gemm_bf16<EP_RESID><<<dim3(32, 8), 256, 0, stream>>>(
      ctx, WtO, x1, 1024, 1024, nullptr, x);
  // MLP sub-block
  ln_kernel<<<NTOK, 256, 0, stream>>>(x1, g2, b2, h);
  gemm_bf16<EP_GELU><<<dim3(32, 32), 256, 0, stream>>>(
      h, WtUp, mbuf, 4096, 1024, bup, nullptr);
  gemm_bf16<EP_DOWN><<<dim3(32, 8), 256, 0, stream>>>(
      mbuf, WtDn, out, 1024, 4096, bdn, x1);
}